// Round 1
// baseline (267.207 us; speedup 1.0000x reference)
//
#include <hip/hip_runtime.h>

#define NB 4
#define NCH 256
#define NTOK 4096
#define DQK 32

typedef _Float16 f16x8 __attribute__((ext_vector_type(8)));
typedef float f32x4 __attribute__((ext_vector_type(4)));

// ---------------- K1: QKV projection (1x1 conv) ----------------
// x[b][c][n] fp32 -> qkT[b][n][0..31]=q, [32..63]=k (fp16, d contiguous)
//                    vbuf[b][c][n] fp16
__global__ __launch_bounds__(256) void qkv_kernel(
    const float* __restrict__ x,
    const float* __restrict__ Wq, const float* __restrict__ bq,
    const float* __restrict__ Wk, const float* __restrict__ bk,
    const float* __restrict__ Wv, const float* __restrict__ bv,
    _Float16* __restrict__ qkT, _Float16* __restrict__ vbuf)
{
    __shared__ float xl[NCH][32];
    __shared__ _Float16 qks[32][64];
    const int tid = threadIdx.x;
    const int b = blockIdx.x >> 7;
    const int n0 = (blockIdx.x & 127) << 5;
    const float* xb = x + (size_t)b * NCH * NTOK + n0;

    for (int e = tid; e < NCH * 32; e += 256) {
        int c = e >> 5, col = e & 31;
        xl[c][col] = xb[(size_t)c * NTOK + col];
    }
    __syncthreads();

    // --- V: one output row per thread, 32 columns ---
    {
        const int o = tid;
        const float* wrow = Wv + o * NCH;
        float acc[32];
        const float bias = bv[o];
        #pragma unroll
        for (int i = 0; i < 32; ++i) acc[i] = bias;
        for (int c4 = 0; c4 < NCH / 4; ++c4) {
            float4 wv = ((const float4*)wrow)[c4];
            #pragma unroll
            for (int u = 0; u < 4; ++u) {
                float w = (u == 0) ? wv.x : (u == 1) ? wv.y : (u == 2) ? wv.z : wv.w;
                const int c = c4 * 4 + u;
                const float4* xr = (const float4*)(&xl[c][0]);
                #pragma unroll
                for (int q4 = 0; q4 < 8; ++q4) {
                    float4 xv = xr[q4];
                    acc[q4*4+0] += w * xv.x;
                    acc[q4*4+1] += w * xv.y;
                    acc[q4*4+2] += w * xv.z;
                    acc[q4*4+3] += w * xv.w;
                }
            }
        }
        _Float16* vo = vbuf + (size_t)(b * NCH + o) * NTOK + n0;
        #pragma unroll
        for (int i = 0; i < 4; ++i) {
            f16x8 pk;
            #pragma unroll
            for (int j = 0; j < 8; ++j) pk[j] = (_Float16)acc[i*8+j];
            ((f16x8*)vo)[i] = pk;
        }
    }

    // --- Q/K: 64 rows x 4 column-quarters spread over 256 threads ---
    {
        const int d_ = tid & 63;          // 0..31 = q rows, 32..63 = k rows
        const int quarter = tid >> 6;     // 8-column group
        const int which = d_ >> 5;
        const int d = d_ & 31;
        const float* wrow = (which ? Wk : Wq) + d * NCH;
        const float bias = (which ? bk : bq)[d];
        float acc[8];
        #pragma unroll
        for (int i = 0; i < 8; ++i) acc[i] = bias;
        for (int c4 = 0; c4 < NCH / 4; ++c4) {
            float4 wv = ((const float4*)wrow)[c4];
            #pragma unroll
            for (int u = 0; u < 4; ++u) {
                float w = (u == 0) ? wv.x : (u == 1) ? wv.y : (u == 2) ? wv.z : wv.w;
                const int c = c4 * 4 + u;
                const float4* xr = (const float4*)(&xl[c][quarter * 8]);
                #pragma unroll
                for (int q4 = 0; q4 < 2; ++q4) {
                    float4 xv = xr[q4];
                    acc[q4*4+0] += w * xv.x;
                    acc[q4*4+1] += w * xv.y;
                    acc[q4*4+2] += w * xv.z;
                    acc[q4*4+3] += w * xv.w;
                }
            }
        }
        #pragma unroll
        for (int j = 0; j < 8; ++j)
            qks[quarter * 8 + j][d_] = (_Float16)acc[j];
    }
    __syncthreads();
    {   // coalesced 16B copy of staged q/k to global, transposed layout
        const int col = tid >> 3, part = tid & 7;
        uint4 val = ((const uint4*)&qks[col][0])[part];
        ((uint4*)(qkT + (size_t)(b * NTOK + n0 + col) * 64))[part] = val;
    }
}

// ---------------- K2: softmax row-sums (1/sum of exp(energy)) ----------------
__global__ __launch_bounds__(256) void rowsum_kernel(
    const _Float16* __restrict__ qkT, float* __restrict__ rs_inv)
{
    const int b = blockIdx.x >> 6;
    const int i0 = (blockIdx.x & 63) << 6;
    const int tid = threadIdx.x;
    const int w = tid >> 6, l = tid & 63;
    const int lrow = l & 15, lgrp = l >> 4;
    const _Float16* base = qkT + (size_t)b * NTOK * 64;

    // A-frag: q rows i0 + w*16 + lrow, d = lgrp*8..+7
    f16x8 qfrag = *(const f16x8*)(base + (size_t)(i0 + w*16 + lrow) * 64 + lgrp * 8);
    float sums[4] = {0.f, 0.f, 0.f, 0.f};
    const f32x4 zero = {0.f, 0.f, 0.f, 0.f};
    #pragma unroll 4
    for (int j0 = 0; j0 < NTOK; j0 += 16) {
        f16x8 kfrag = *(const f16x8*)(base + (size_t)(j0 + lrow) * 64 + 32 + lgrp * 8);
        f32x4 s = __builtin_amdgcn_mfma_f32_16x16x32_f16(qfrag, kfrag, zero, 0, 0, 0);
        #pragma unroll
        for (int r = 0; r < 4; ++r) sums[r] += __expf(s[r]);
    }
    #pragma unroll
    for (int m = 1; m < 16; m <<= 1) {
        #pragma unroll
        for (int r = 0; r < 4; ++r) sums[r] += __shfl_xor(sums[r], m, 64);
    }
    if (lrow == 0) {
        #pragma unroll
        for (int r = 0; r < 4; ++r)
            rs_inv[b * NTOK + i0 + w*16 + lgrp*4 + r] = 1.0f / sums[r];
    }
}

// ---------------- K3: fused energy -> softmax write -> PV -> residual ----------------
// block: (b, 64-row i-tile, 128-col c-half). 4 waves: wave w owns S rows w*16..+15
// and PV c-range c0 + w*32..+31. P relayed via padded LDS, double-buffered.
__global__ __launch_bounds__(256, 2) void attn_pv_kernel(
    const _Float16* __restrict__ qkT, const _Float16* __restrict__ vbuf,
    const float* __restrict__ rs_inv, const float* __restrict__ x,
    const float* __restrict__ gamma, float* __restrict__ out, float* __restrict__ atn)
{
    __shared__ _Float16 P_lds[2][64][40];   // +8 pad -> 80B row stride, ~2-way banks
    const int id = blockIdx.x;
    // XCD-bijective swizzle: id%8 = 2b + (it&1) pins batch b's v to XCD pair
    const int r_ = id & 7, q_ = id >> 3;
    const int b = r_ >> 1;
    const int it = (q_ >> 1) * 2 + (r_ & 1);
    const int ch = q_ & 1;
    const int i0 = it << 6;
    const int c0 = ch << 7;
    const int tid = threadIdx.x;
    const int w = tid >> 6, l = tid & 63;
    const int lrow = l & 15, lgrp = l >> 4;

    const _Float16* qk_b = qkT + (size_t)b * NTOK * 64;
    const _Float16* v_b  = vbuf + (size_t)b * NCH * NTOK;
    float* atn_b = atn + (size_t)b * NTOK * NTOK;

    f16x8 qfrag = *(const f16x8*)(qk_b + (size_t)(i0 + w*16 + lrow) * 64 + lgrp * 8);
    float rsi[4];
    #pragma unroll
    for (int r = 0; r < 4; ++r)
        rsi[r] = rs_inv[b * NTOK + i0 + w*16 + lgrp*4 + r];

    const f32x4 zero = {0.f, 0.f, 0.f, 0.f};
    f32x4 acc[4][2];
    #pragma unroll
    for (int rt = 0; rt < 4; ++rt)
        #pragma unroll
        for (int ct = 0; ct < 2; ++ct) acc[rt][ct] = zero;

    for (int jt = 0; jt < NTOK / 32; ++jt) {
        const int j0 = jt * 32;
        const int buf = jt & 1;
        // S = q^T k for my 16 rows x 32 j (2 MFMAs, K=32 = full d)
        f32x4 p[2];
        #pragma unroll
        for (int t = 0; t < 2; ++t) {
            f16x8 kfrag = *(const f16x8*)(qk_b + (size_t)(j0 + t*16 + lrow) * 64 + 32 + lgrp * 8);
            p[t] = __builtin_amdgcn_mfma_f32_16x16x32_f16(qfrag, kfrag, zero, 0, 0, 0);
        }
        // normalize, emit attention (fp32) + P (fp16 -> LDS)
        #pragma unroll
        for (int t = 0; t < 2; ++t) {
            #pragma unroll
            for (int r = 0; r < 4; ++r) {
                float pv = __expf(p[t][r]) * rsi[r];
                if (ch == 0)
                    atn_b[(size_t)(i0 + w*16 + lgrp*4 + r) * NTOK + (j0 + t*16 + lrow)] = pv;
                P_lds[buf][w*16 + lgrp*4 + r][t*16 + lrow] = (_Float16)pv;
            }
        }
        __syncthreads();
        // PV: all 4 row-tiles x my 2 c-tiles, K=32 (whole j-tile)
        #pragma unroll
        for (int rt = 0; rt < 4; ++rt) {
            f16x8 pfrag = *(const f16x8*)(&P_lds[buf][rt*16 + lrow][lgrp * 8]);
            #pragma unroll
            for (int ct = 0; ct < 2; ++ct) {
                const int c = c0 + w*32 + ct*16 + lrow;
                f16x8 vfrag = *(const f16x8*)(v_b + (size_t)c * NTOK + j0 + lgrp * 8);
                acc[rt][ct] = __builtin_amdgcn_mfma_f32_16x16x32_f16(pfrag, vfrag, acc[rt][ct], 0, 0, 0);
            }
        }
    }

    // epilogue: out[b][c][i] = gamma*acc + x, 16B stores (4 consecutive i per lane)
    const float g = gamma[0];
    #pragma unroll
    for (int rt = 0; rt < 4; ++rt) {
        #pragma unroll
        for (int ct = 0; ct < 2; ++ct) {
            const int c = c0 + w*32 + ct*16 + lrow;
            const size_t bse = ((size_t)(b * NCH + c)) * NTOK + i0 + rt*16 + lgrp*4;
            float4 xv = *(const float4*)(x + bse);
            float4 o;
            o.x = g * acc[rt][ct][0] + xv.x;
            o.y = g * acc[rt][ct][1] + xv.y;
            o.z = g * acc[rt][ct][2] + xv.z;
            o.w = g * acc[rt][ct][3] + xv.w;
            *(float4*)(out + bse) = o;
        }
    }
}

extern "C" void kernel_launch(void* const* d_in, const int* in_sizes, int n_in,
                              void* d_out, int out_size, void* d_ws, size_t ws_size,
                              hipStream_t stream) {
    const float* x     = (const float*)d_in[0];
    const float* Wq    = (const float*)d_in[1];
    const float* bq    = (const float*)d_in[2];
    const float* Wk    = (const float*)d_in[3];
    const float* bk    = (const float*)d_in[4];
    const float* Wv    = (const float*)d_in[5];
    const float* bv    = (const float*)d_in[6];
    const float* gamma = (const float*)d_in[7];

    float* out = (float*)d_out;
    float* atn = out + (size_t)NB * NCH * NTOK;   // outputs concatenated: (out, attention)

    _Float16* qkT  = (_Float16*)d_ws;                         // 4*4096*64  = 2 MB
    _Float16* vbuf = qkT + (size_t)NB * NTOK * 64;            // 4*256*4096 = 8 MB
    float* rs_inv  = (float*)(vbuf + (size_t)NB * NCH * NTOK);// 64 KB

    qkv_kernel<<<512, 256, 0, stream>>>(x, Wq, bq, Wk, bk, Wv, bv, qkT, vbuf);
    rowsum_kernel<<<256, 256, 0, stream>>>(qkT, rs_inv);
    attn_pv_kernel<<<512, 256, 0, stream>>>(qkT, vbuf, rs_inv, x, gamma, out, atn);
}